// Round 6
// baseline (743.617 us; speedup 1.0000x reference)
//
#include <hip/hip_runtime.h>
#include <hip/hip_bf16.h>

// SDE Euler-Maruyama: x_{k+1} = x_k + dt*(x_k @ A^T) + (sigma*sqrt(dt))*dW_k
// out[0] = x0, out[k+1] = x_{k+1}, out shape [1001, 1024, 256].
//
// R1 880us: 1 wave/SIMD latency-bound. R2 849us: lgkm-only barriers.
// R3 973us: fused C/D update regressed AT 1 WAVE/SIMD (scalar I/O exposed).
// R4 632us: split-role, 512thr = 2 waves/SIMD. R5 644us: 4 waves/SIMD flat
// (barrier-locked waves + 2x redundant frag ds_reads).
// R6: fused role AT 2 waves/SIMD: wave w owns MFMA cols w*32..+31 AND updates
// them in C/D layout (lanes 0-15 hold the 4 real paths as regs). One LDS
// handoff (xb, double-buffered) + ONE lgkm-only barrier per step; no dr tile.
// Scalar 64B-coalesced dW/out I/O hides under the MFMA phase.

typedef __attribute__((ext_vector_type(2))) float fvec2;
typedef __attribute__((ext_vector_type(4))) float fvec4;
typedef __attribute__((ext_vector_type(8))) short svec8;
typedef __attribute__((ext_vector_type(4))) float f32x4;

constexpr int D = 256;
constexpr int BATCH = 1024;
constexpr int BD = BATCH * D;
constexpr int NSTEPS = 1000;
constexpr float DT = 0.001f;
constexpr float SQRT_DT = 0.03162277660168379f;  // sqrt(0.001)

__device__ __forceinline__ unsigned short f2bf(float f) {
  // round-to-nearest-even f32 -> bf16
  unsigned int u = __float_as_uint(f);
  u += 0x7FFFu + ((u >> 16) & 1u);
  return (unsigned short)(u >> 16);
}

// LDS-only barrier: no vmcnt drain (global loads/stores stay in flight).
__device__ __forceinline__ void lds_barrier() {
  __builtin_amdgcn_sched_barrier(0);
  asm volatile("s_waitcnt lgkmcnt(0)" ::: "memory");
  __builtin_amdgcn_s_barrier();
  __builtin_amdgcn_sched_barrier(0);
}

// xb element index for (path r, dim c): (r<<8) + (c ^ (r<<5))  [u16 units]

__global__ __launch_bounds__(512, 2)
void sde_em_kernel(const float* __restrict__ x0, const float* __restrict__ Amat,
                   const float* __restrict__ sigma, const float* __restrict__ dW,
                   float* __restrict__ out) {
  __shared__ __align__(16) unsigned short xb[2][4 * 256];  // double-buffered bf16 x

  const int t = threadIdx.x;
  const int w = t >> 6;          // wave 0..7: owns cols w*32 .. w*32+31
  const int l = t & 63;
  const int l16 = l & 15;
  const int q = l >> 4;
  const int rr = l16 & 3;        // A-frag row: paths 0-3 (rows 4-15 duplicate)

  // ---- one-time: A fragments (GEMM B-operand), bf16, registers ----
  // B-frag (16x16x32): lane holds col n = l&15 (+16*tt), k = q*8 + i (+32*kt)
  svec8 bfr[2][8];
#pragma unroll
  for (int tt = 0; tt < 2; ++tt) {
#pragma unroll
    for (int kt = 0; kt < 8; ++kt) {
      const float* src =
          Amat + (size_t)((w << 5) + (tt << 4) + l16) * D + (kt << 5) + (q << 3);
      fvec4 a0 = *(const fvec4*)(src);
      fvec4 a1 = *(const fvec4*)(src + 4);
      svec8 b;
      b[0] = (short)f2bf(a0[0]); b[1] = (short)f2bf(a0[1]);
      b[2] = (short)f2bf(a0[2]); b[3] = (short)f2bf(a0[3]);
      b[4] = (short)f2bf(a1[0]); b[5] = (short)f2bf(a1[1]);
      b[6] = (short)f2bf(a1[2]); b[7] = (short)f2bf(a1[3]);
      bfr[tt][kt] = b;
    }
  }

  // ---- prologue (vectorized, all 512 threads): out[0]=x0, seed xb[0] ----
  {
    const int p2 = t >> 7;             // path 0..3
    const int c2 = (t & 127) << 1;     // even dim
    const size_t g2 = (size_t)((blockIdx.x << 2) + p2) * D + c2;
    fvec2 v = *(const fvec2*)(x0 + g2);
    __builtin_nontemporal_store(v, (fvec2*)(out + g2));
    *(unsigned int*)&xb[0][(p2 << 8) + (c2 ^ (p2 << 5))] =
        (unsigned int)f2bf(v[0]) | ((unsigned int)f2bf(v[1]) << 16);
  }

  // ---- fused C/D-layout state: lanes 0-15 hold x[path r][col w*32+tt*16+l16]
  const bool act = (l < 16);
  const size_t gc = (size_t)(blockIdx.x << 2) * D + (w << 5) + l16;  // +r*D+tt*16
  float xs[2][4], dwA[2][4], dwB[2][4];
  float sg0 = 0.f, sg1 = 0.f;
  if (act) {
    sg0 = sigma[(w << 5) + l16] * SQRT_DT;
    sg1 = sigma[(w << 5) + 16 + l16] * SQRT_DT;
#pragma unroll
    for (int tt = 0; tt < 2; ++tt)
#pragma unroll
      for (int r = 0; r < 4; ++r) {
        xs[tt][r] = x0[gc + r * D + (tt << 4)];
        dwA[tt][r] = __builtin_nontemporal_load(dW + gc + r * D + (tt << 4));
        dwB[tt][r] = __builtin_nontemporal_load(dW + BD + gc + r * D + (tt << 4));
      }
  }

  __syncthreads();

#define STEP(n_, CUR, RB, WB)                                                  \
  {                                                                            \
    /* MFMA: drift cols w*32..+31, all 4 paths (rows 0-3 -> lanes 0-15) */     \
    f32x4 acc0 = (f32x4){0.f, 0.f, 0.f, 0.f};                                  \
    f32x4 acc1 = (f32x4){0.f, 0.f, 0.f, 0.f};                                  \
    _Pragma("unroll") for (int kt = 0; kt < 8; ++kt) {                         \
      svec8 a = *(const svec8*)                                                \
          &xb[RB][(rr << 8) + (((kt << 5) + (q << 3)) ^ (rr << 5))];           \
      acc0 = __builtin_amdgcn_mfma_f32_16x16x32_bf16(a, bfr[0][kt], acc0,      \
                                                     0, 0, 0);                 \
      acc1 = __builtin_amdgcn_mfma_f32_16x16x32_bf16(a, bfr[1][kt], acc1,      \
                                                     0, 0, 0);                 \
    }                                                                          \
    if (act) {                                                                 \
      /* in-register update; C/D: col=lane&15, row(path)=reg on lanes 0-15 */  \
      _Pragma("unroll") for (int r = 0; r < 4; ++r) {                          \
        xs[0][r] =                                                             \
            __builtin_fmaf(DT, acc0[r],                                        \
                           __builtin_fmaf(sg0, CUR[0][r], xs[0][r]));          \
        xs[1][r] =                                                             \
            __builtin_fmaf(DT, acc1[r],                                        \
                           __builtin_fmaf(sg1, CUR[1][r], xs[1][r]));          \
      }                                                                        \
      /* refill CUR with dW[n+2] (consumed; one full step of latency cover) */ \
      const int nn_ = ((n_) + 2 < NSTEPS) ? ((n_) + 2) : (NSTEPS - 1);         \
      const float* dwp_ = dW + (size_t)nn_ * BD + gc;                          \
      float* op_ = out + (size_t)((n_) + 1) * BD + gc;                         \
      _Pragma("unroll") for (int r = 0; r < 4; ++r) {                          \
        CUR[0][r] = __builtin_nontemporal_load(dwp_ + r * D);                  \
        CUR[1][r] = __builtin_nontemporal_load(dwp_ + r * D + 16);             \
        __builtin_nontemporal_store(xs[0][r], op_ + r * D);                    \
        __builtin_nontemporal_store(xs[1][r], op_ + r * D + 16);               \
        xb[WB][(r << 8) + (((w << 5) + l16) ^ (r << 5))] = f2bf(xs[0][r]);     \
        xb[WB][(r << 8) + (((w << 5) + 16 + l16) ^ (r << 5))] =                \
            f2bf(xs[1][r]);                                                    \
      }                                                                        \
    }                                                                          \
    lds_barrier();                                                             \
  }

  for (int n = 0; n < NSTEPS; n += 2) {
    STEP(n, dwA, 0, 1);
    STEP(n + 1, dwB, 1, 0);
  }
#undef STEP
}

extern "C" void kernel_launch(void* const* d_in, const int* in_sizes, int n_in,
                              void* d_out, int out_size, void* d_ws, size_t ws_size,
                              hipStream_t stream) {
  const float* x0    = (const float*)d_in[0];
  const float* Amat  = (const float*)d_in[1];
  const float* sigma = (const float*)d_in[2];
  const float* dW    = (const float*)d_in[3];
  float* out = (float*)d_out;
  sde_em_kernel<<<dim3(256), dim3(512), 0, stream>>>(x0, Amat, sigma, dW, out);
}

// Round 7
// 715.643 us; speedup vs baseline: 1.0391x; 1.0391x over previous
//
#include <hip/hip_runtime.h>
#include <hip/hip_bf16.h>

// SDE Euler-Maruyama: x_{k+1} = x_k + dt*(x_k @ A^T) + (sigma*sqrt(dt))*dW_k
// out[0] = x0, out[k+1] = x_{k+1}, out shape [1001, 1024, 256].
//
// R1 880us: 1 wave/SIMD latency-bound. R2 849us: lgkm-only barriers.
// R3 973us / R6 743us: fused C/D update regressed (serialized I/O on 16 lanes).
// R4 632us: split-role, 2 waves/SIMD, MfmaUtil 35%. R5 644us: 4 waves ONE
// block = barrier-locked, no gain.
// R7: PHASE OVERLAP VIA INDEPENDENT BARRIERS: 512 blocks x 2 paths = 2
// blocks/CU. Block A's MFMA issues while block B stalls in its LDS/update/
// barrier segment (per-workgroup s_barrier). Costs 8x M-pad (2 real rows of
// 16) = 2x MFMA issue/CU -- cheap vs the ~50% stall fraction it covers.
// Block: 256 thr = 4 waves; wave owns 64 cols (4 chains x 8 MFMA); update
// thread owns (path p, dims c and c+128).

typedef __attribute__((ext_vector_type(4))) float fvec4;
typedef __attribute__((ext_vector_type(8))) short svec8;
typedef __attribute__((ext_vector_type(4))) float f32x4;

constexpr int D = 256;
constexpr int BATCH = 1024;
constexpr int BD = BATCH * D;
constexpr int NSTEPS = 1000;
constexpr float DT = 0.001f;
constexpr float SQRT_DT = 0.03162277660168379f;  // sqrt(0.001)

__device__ __forceinline__ unsigned short f2bf(float f) {
  // round-to-nearest-even f32 -> bf16
  unsigned int u = __float_as_uint(f);
  u += 0x7FFFu + ((u >> 16) & 1u);
  return (unsigned short)(u >> 16);
}

// LDS-only barrier: no vmcnt drain (global loads/stores stay in flight).
__device__ __forceinline__ void lds_barrier() {
  __builtin_amdgcn_sched_barrier(0);
  asm volatile("s_waitcnt lgkmcnt(0)" ::: "memory");
  __builtin_amdgcn_s_barrier();
  __builtin_amdgcn_sched_barrier(0);
}

__global__ __launch_bounds__(256, 2)
void sde_em_kernel(const float* __restrict__ x0, const float* __restrict__ Amat,
                   const float* __restrict__ sigma, const float* __restrict__ dW,
                   float* __restrict__ out) {
  // xb: double-buffered bf16 x, 2 paths x 256 dims, swizzled (^ row<<5, u16)
  __shared__ __align__(16) unsigned short xb[2][2 * 256];
  // dr: fp32 drift, 2 paths x 256 dims
  __shared__ __align__(16) float dr[2 * 256];

  const int t = threadIdx.x;
  const int w = t >> 6;          // wave 0..3: owns cols w*64 .. w*64+63
  const int l = t & 63;
  const int l16 = l & 15;
  const int q = l >> 4;
  const int rr = l16 & 1;        // A-frag row: paths 0-1 (rows 2-15 duplicate)

  // ---- one-time: A fragments (GEMM B-operand), bf16, registers ----
  // B-frag (16x16x32): lane holds col n = l&15 (+16*tt), k = q*8 + i (+32*kt)
  svec8 bfr[4][8];
#pragma unroll
  for (int tt = 0; tt < 4; ++tt) {
#pragma unroll
    for (int kt = 0; kt < 8; ++kt) {
      const float* src =
          Amat + (size_t)((w << 6) + (tt << 4) + l16) * D + (kt << 5) + (q << 3);
      fvec4 a0 = *(const fvec4*)(src);
      fvec4 a1 = *(const fvec4*)(src + 4);
      svec8 b;
      b[0] = (short)f2bf(a0[0]); b[1] = (short)f2bf(a0[1]);
      b[2] = (short)f2bf(a0[2]); b[3] = (short)f2bf(a0[3]);
      b[4] = (short)f2bf(a1[0]); b[5] = (short)f2bf(a1[1]);
      b[6] = (short)f2bf(a1[2]); b[7] = (short)f2bf(a1[3]);
      bfr[tt][kt] = b;
    }
  }

  // ---- update role: thread owns (path p, dims c and c+128) ----
  const int p = t >> 7;          // path 0..1
  const int c = t & 127;         // dim 0..127 (+128 for second item)
  const size_t g0 = (size_t)((blockIdx.x << 1) + p) * D + c;
  const int xw = (p << 8) + (c ^ (p << 5));  // xb u16 index (bit7 clear; +128 ok)

  const float sg0 = sigma[c] * SQRT_DT;
  const float sg1 = sigma[c + 128] * SQRT_DT;
  float xs0 = x0[g0];
  float xs1 = x0[g0 + 128];

  // out[0] = x0; seed xb[0]
  __builtin_nontemporal_store(xs0, out + g0);
  __builtin_nontemporal_store(xs1, out + g0 + 128);
  xb[0][xw] = f2bf(xs0);
  xb[0][xw + 128] = f2bf(xs1);

  // 2-deep dW prefetch
  float dwA0 = __builtin_nontemporal_load(dW + g0);
  float dwA1 = __builtin_nontemporal_load(dW + g0 + 128);
  float dwB0 = __builtin_nontemporal_load(dW + BD + g0);
  float dwB1 = __builtin_nontemporal_load(dW + BD + g0 + 128);

  __syncthreads();

#define STEP(n_, C0, C1, RB, WB)                                               \
  {                                                                            \
    /* MFMA: drift cols w*64..+63, paths 0-1 (C/D rows 0-1, lanes 0-15) */     \
    f32x4 acc[4];                                                              \
    acc[0] = (f32x4){0.f, 0.f, 0.f, 0.f};                                      \
    acc[1] = (f32x4){0.f, 0.f, 0.f, 0.f};                                      \
    acc[2] = (f32x4){0.f, 0.f, 0.f, 0.f};                                      \
    acc[3] = (f32x4){0.f, 0.f, 0.f, 0.f};                                      \
    _Pragma("unroll") for (int kt = 0; kt < 8; ++kt) {                         \
      svec8 a = *(const svec8*)                                                \
          &xb[RB][(rr << 8) + (((kt << 5) + (q << 3)) ^ (rr << 5))];           \
      _Pragma("unroll") for (int tt = 0; tt < 4; ++tt) acc[tt] =               \
          __builtin_amdgcn_mfma_f32_16x16x32_bf16(a, bfr[tt][kt], acc[tt], 0,  \
                                                  0, 0);                       \
    }                                                                          \
    /* C/D: col = lane&15, row = (lane>>4)*4 + reg; real rows 0,1 */           \
    if (l < 16) {                                                              \
      _Pragma("unroll") for (int tt = 0; tt < 4; ++tt) {                       \
        dr[(w << 6) + (tt << 4) + l16] = acc[tt][0];                           \
        dr[256 + (w << 6) + (tt << 4) + l16] = acc[tt][1];                     \
      }                                                                        \
    }                                                                          \
    lds_barrier();                                                             \
    const float df0 = dr[(p << 8) + c];                                        \
    const float df1 = dr[(p << 8) + c + 128];                                  \
    xs0 = __builtin_fmaf(DT, df0, __builtin_fmaf(sg0, C0, xs0));               \
    xs1 = __builtin_fmaf(DT, df1, __builtin_fmaf(sg1, C1, xs1));               \
    float* op_ = out + (size_t)((n_) + 1) * BD + g0;                           \
    __builtin_nontemporal_store(xs0, op_);                                     \
    __builtin_nontemporal_store(xs1, op_ + 128);                               \
    xb[WB][xw] = f2bf(xs0);                                                    \
    xb[WB][xw + 128] = f2bf(xs1);                                              \
    const int nn_ = ((n_) + 2 < NSTEPS) ? ((n_) + 2) : (NSTEPS - 1);           \
    const float* dwp_ = dW + (size_t)nn_ * BD + g0;                            \
    C0 = __builtin_nontemporal_load(dwp_);                                     \
    C1 = __builtin_nontemporal_load(dwp_ + 128);                               \
    lds_barrier();                                                             \
  }

  for (int n = 0; n < NSTEPS; n += 2) {
    STEP(n, dwA0, dwA1, 0, 1);
    STEP(n + 1, dwB0, dwB1, 1, 0);
  }
#undef STEP
}

extern "C" void kernel_launch(void* const* d_in, const int* in_sizes, int n_in,
                              void* d_out, int out_size, void* d_ws, size_t ws_size,
                              hipStream_t stream) {
  const float* x0    = (const float*)d_in[0];
  const float* Amat  = (const float*)d_in[1];
  const float* sigma = (const float*)d_in[2];
  const float* dW    = (const float*)d_in[3];
  float* out = (float*)d_out;
  sde_em_kernel<<<dim3(512), dim3(256), 0, stream>>>(x0, Amat, sigma, dW, out);
}

// Round 8
// 601.530 us; speedup vs baseline: 1.2362x; 1.1897x over previous
//
#include <hip/hip_runtime.h>
#include <hip/hip_bf16.h>

// SDE Euler-Maruyama: x_{k+1} = x_k + dt*(x_k @ A^T) + (sigma*sqrt(dt))*dW_k
// out[0] = x0, out[k+1] = x_{k+1}, out shape [1001, 1024, 256].
//
// R1 880 / R2 849 / R3 973 / R4 632 / R5 644 / R6 743 / R7 715.
// R4 (split-role, 2 waves/SIMD) was best; its cost = 2 barriers + dr LDS
// round-trip per step. R7 proved phase-overlap works but 2x MFMA pad loses.
// R8: REPLICA-FUSED UPDATE. In the M=16 tile, A-rows 4-15 duplicate paths
// 0-3, so C/D rows 4-15 duplicate the drift: every 16-lane group already
// holds all 4 paths' drift (reg r = path r). Lane group g updates path g
// (select acc[.][g] via 3 cndmask) -> all 64 lanes active, NO dr tile, ONE
// lgkm-only barrier per step, zero extra MFMA. Everything else = R4.

typedef __attribute__((ext_vector_type(2))) float fvec2;
typedef __attribute__((ext_vector_type(4))) float fvec4;
typedef __attribute__((ext_vector_type(8))) short svec8;
typedef __attribute__((ext_vector_type(4))) float f32x4;

constexpr int D = 256;
constexpr int BATCH = 1024;
constexpr int BD = BATCH * D;
constexpr int NSTEPS = 1000;
constexpr float DT = 0.001f;
constexpr float SQRT_DT = 0.03162277660168379f;  // sqrt(0.001)

__device__ __forceinline__ unsigned short f2bf(float f) {
  // round-to-nearest-even f32 -> bf16
  unsigned int u = __float_as_uint(f);
  u += 0x7FFFu + ((u >> 16) & 1u);
  return (unsigned short)(u >> 16);
}

// LDS-only barrier: no vmcnt drain (global loads/stores stay in flight).
__device__ __forceinline__ void lds_barrier() {
  __builtin_amdgcn_sched_barrier(0);
  asm volatile("s_waitcnt lgkmcnt(0)" ::: "memory");
  __builtin_amdgcn_s_barrier();
  __builtin_amdgcn_sched_barrier(0);
}

// select v[g] for g in 0..3 (g uniform per 16-lane group -> 3 v_cndmask)
__device__ __forceinline__ float sel4(f32x4 v, int g) {
  float r = v[0];
  r = (g == 1) ? v[1] : r;
  r = (g == 2) ? v[2] : r;
  r = (g == 3) ? v[3] : r;
  return r;
}

__global__ __launch_bounds__(512, 2)
void sde_em_kernel(const float* __restrict__ x0, const float* __restrict__ Amat,
                   const float* __restrict__ sigma, const float* __restrict__ dW,
                   float* __restrict__ out) {
  // xb: double-buffered bf16 x, 4 paths x 256 dims, swizzled (^ row<<5, u16)
  __shared__ __align__(16) unsigned short xb[2][4 * 256];

  const int t = threadIdx.x;
  const int w = t >> 6;          // wave 0..7: owns cols w*32 .. w*32+31
  const int l = t & 63;
  const int l16 = l & 15;
  const int q = l >> 4;          // lane group 0..3
  const int rr = l16 & 3;        // A-frag row -> path (rows 4-15 duplicate 0-3)

  // ---- one-time: A fragments (GEMM B-operand), bf16, registers ----
  // B-frag (16x16x32): lane holds col n = l&15 (+16*tt), k = q*8 + i (+32*kt)
  svec8 bfr[2][8];
#pragma unroll
  for (int tt = 0; tt < 2; ++tt) {
#pragma unroll
    for (int kt = 0; kt < 8; ++kt) {
      const float* src =
          Amat + (size_t)((w << 5) + (tt << 4) + l16) * D + (kt << 5) + (q << 3);
      fvec4 a0 = *(const fvec4*)(src);
      fvec4 a1 = *(const fvec4*)(src + 4);
      svec8 b;
      b[0] = (short)f2bf(a0[0]); b[1] = (short)f2bf(a0[1]);
      b[2] = (short)f2bf(a0[2]); b[3] = (short)f2bf(a0[3]);
      b[4] = (short)f2bf(a1[0]); b[5] = (short)f2bf(a1[1]);
      b[6] = (short)f2bf(a1[2]); b[7] = (short)f2bf(a1[3]);
      bfr[tt][kt] = b;
    }
  }

  // ---- prologue (vectorized, all 512 threads): out[0]=x0, seed xb[0] ----
  {
    const int p2 = t >> 7;             // path 0..3
    const int c2 = (t & 127) << 1;     // even dim
    const size_t g2 = (size_t)((blockIdx.x << 2) + p2) * D + c2;
    fvec2 v = *(const fvec2*)(x0 + g2);
    __builtin_nontemporal_store(v, (fvec2*)(out + g2));
    *(unsigned int*)&xb[0][(p2 << 8) + (c2 ^ (p2 << 5))] =
        (unsigned int)f2bf(v[0]) | ((unsigned int)f2bf(v[1]) << 16);
  }

  // ---- fused update role: lane (group q, l16) owns path q, cols
  //      w*32+l16 and w*32+16+l16 ----
  const int c0 = (w << 5) + l16;           // first owned col
  const size_t go = (size_t)((blockIdx.x << 2) + q) * D + c0;  // +16 for second
  const int xw0 = (q << 8) + (c0 ^ (q << 5));
  const int xw1 = (q << 8) + ((c0 + 16) ^ (q << 5));

  const float sg0 = sigma[c0] * SQRT_DT;
  const float sg1 = sigma[c0 + 16] * SQRT_DT;
  float xs0 = x0[go];
  float xs1 = x0[go + 16];

  // 2-deep dW prefetch
  float dwA0 = __builtin_nontemporal_load(dW + go);
  float dwA1 = __builtin_nontemporal_load(dW + go + 16);
  float dwB0 = __builtin_nontemporal_load(dW + BD + go);
  float dwB1 = __builtin_nontemporal_load(dW + BD + go + 16);

  __syncthreads();

#define STEP(n_, C0, C1, RB, WB)                                               \
  {                                                                            \
    f32x4 acc0 = (f32x4){0.f, 0.f, 0.f, 0.f};                                  \
    f32x4 acc1 = (f32x4){0.f, 0.f, 0.f, 0.f};                                  \
    _Pragma("unroll") for (int kt = 0; kt < 8; ++kt) {                         \
      svec8 a = *(const svec8*)                                                \
          &xb[RB][(rr << 8) + (((kt << 5) + (q << 3)) ^ (rr << 5))];           \
      acc0 = __builtin_amdgcn_mfma_f32_16x16x32_bf16(a, bfr[0][kt], acc0,      \
                                                     0, 0, 0);                 \
      acc1 = __builtin_amdgcn_mfma_f32_16x16x32_bf16(a, bfr[1][kt], acc1,      \
                                                     0, 0, 0);                 \
    }                                                                          \
    /* group q holds all 4 paths' drift (reg r = path r); take path q */       \
    const float df0 = sel4(acc0, q);                                           \
    const float df1 = sel4(acc1, q);                                           \
    xs0 = __builtin_fmaf(DT, df0, __builtin_fmaf(sg0, C0, xs0));               \
    xs1 = __builtin_fmaf(DT, df1, __builtin_fmaf(sg1, C1, xs1));               \
    float* op_ = out + (size_t)((n_) + 1) * BD + go;                           \
    __builtin_nontemporal_store(xs0, op_);                                     \
    __builtin_nontemporal_store(xs1, op_ + 16);                                \
    xb[WB][xw0] = f2bf(xs0);                                                   \
    xb[WB][xw1] = f2bf(xs1);                                                   \
    const int nn_ = ((n_) + 2 < NSTEPS) ? ((n_) + 2) : (NSTEPS - 1);           \
    const float* dwp_ = dW + (size_t)nn_ * BD + go;                            \
    C0 = __builtin_nontemporal_load(dwp_);                                     \
    C1 = __builtin_nontemporal_load(dwp_ + 16);                                \
    lds_barrier();                                                             \
  }

  for (int n = 0; n < NSTEPS; n += 2) {
    STEP(n, dwA0, dwA1, 0, 1);
    STEP(n + 1, dwB0, dwB1, 1, 0);
  }
#undef STEP
}

extern "C" void kernel_launch(void* const* d_in, const int* in_sizes, int n_in,
                              void* d_out, int out_size, void* d_ws, size_t ws_size,
                              hipStream_t stream) {
  const float* x0    = (const float*)d_in[0];
  const float* Amat  = (const float*)d_in[1];
  const float* sigma = (const float*)d_in[2];
  const float* dW    = (const float*)d_in[3];
  float* out = (float*)d_out;
  sde_em_kernel<<<dim3(256), dim3(512), 0, stream>>>(x0, Amat, sigma, dW, out);
}